// Round 7
// baseline (1133.501 us; speedup 1.0000x reference)
//
#include <hip/hip_runtime.h>

#define KOFF 27
#define MPAIR 100000
#define NPAIR (KOFF * MPAIR)        // 2,700,000
#define NIN 200000
#define NOUT 400000
#define CIN 32
#define COUT 32

#define IN_RPB 128                  // in_rows per mv2 bin
#define NBIN_IN 1563                // ceil(200000/128)
#define OUT_RPB 256                 // out rows per gather bin
#define NBIN_OUT 1563               // ceil(400000/256)
#define LCAP 2048                   // per-bin LDS staging capacity (avg fill 1728)
#define BPB 8192
#define NBLK_AB ((NPAIR + BPB - 1) / BPB)   // 330
#define SPILL_CAP 65536

// ---------- workspace layout (bytes) ----------
#define O_CNTI   ((size_t)0)         // counts_in  1563*4 (pad 8192)
#define O_CNTO   ((size_t)8192)      // counts_out
#define O_BASI   ((size_t)16384)     // bases_in   1564*4
#define O_BASO   ((size_t)24576)     // bases_out
#define O_CURI   ((size_t)32768)     // cursors_in
#define O_CURO   ((size_t)40960)     // cursors_out
#define O_SPCNT  ((size_t)49152)     // 256
#define O_SPILL  ((size_t)49408)     // 65536*4 -> 311,552
#define O_BINI   ((size_t)524288)    // binned_in  2.7M*4 -> 11,324,288
#define O_BINO   ((size_t)11324288)  // binned_out 2.7M*4 -> 22,124,288
#define O_PEROFF ((size_t)22124288)  // per_off 2.7M*64B  -> 194,924,288
#define WS_NEED  ((size_t)194924288)

__device__ __forceinline__ unsigned int bf16pair(float a, float b) {
    unsigned int ua = __float_as_uint(a), ub = __float_as_uint(b);
    ua = (ua + 0x7fffu + ((ua >> 16) & 1u)) >> 16;   // RNE
    ub = (ub + 0x7fffu + ((ub >> 16) & 1u)) >> 16;
    return ua | (ub << 16);
}
__device__ __forceinline__ float bf2f(unsigned short v) {
    return __uint_as_float(((unsigned int)v) << 16);
}

// ---------- A1: histogram both maps ----------
__global__ __launch_bounds__(256) void hist_kernel(
    const int* __restrict__ in_map, const int* __restrict__ out_map,
    int* __restrict__ cnt_in, int* __restrict__ cnt_out)
{
    __shared__ int hi[NBIN_IN];
    __shared__ int ho[NBIN_OUT];
    const int t = threadIdx.x;
    const int base = blockIdx.x * BPB;
    for (int c = t; c < NBIN_IN; c += 256) hi[c] = 0;
    for (int c = t; c < NBIN_OUT; c += 256) ho[c] = 0;
    __syncthreads();
    for (int i = t; i < BPB; i += 256) {
        int p = base + i;
        if (p < NPAIR) {
            atomicAdd(&hi[in_map[p] >> 7], 1);
            atomicAdd(&ho[out_map[p] >> 8], 1);
        }
    }
    __syncthreads();
    for (int c = t; c < NBIN_IN; c += 256) if (hi[c]) atomicAdd(&cnt_in[c], hi[c]);
    for (int c = t; c < NBIN_OUT; c += 256) if (ho[c]) atomicAdd(&cnt_out[c], ho[c]);
}

// ---------- A2: exclusive scan of both count arrays (single block) ----------
__global__ __launch_bounds__(256) void scan_kernel(
    const int* __restrict__ cnt_in, const int* __restrict__ cnt_out,
    int* __restrict__ bas_in, int* __restrict__ bas_out,
    int* __restrict__ cur_in, int* __restrict__ cur_out)
{
    __shared__ int lsum[256];
    const int t = threadIdx.x;
    for (int a = 0; a < 2; ++a) {
        const int* cnt = a ? cnt_out : cnt_in;
        int* bas = a ? bas_out : bas_in;
        int* cur = a ? cur_out : cur_in;
        const int n = a ? NBIN_OUT : NBIN_IN;
        int v[7]; int s = 0;
#pragma unroll
        for (int j = 0; j < 7; ++j) {
            int i = t * 7 + j;
            v[j] = (i < n) ? cnt[i] : 0;
            s += v[j];
        }
        lsum[t] = s;
        __syncthreads();
        for (int off = 1; off < 256; off <<= 1) {
            int w = (t >= off) ? lsum[t - off] : 0;
            __syncthreads();
            lsum[t] += w;
            __syncthreads();
        }
        int run = lsum[t] - s;                 // exclusive prefix of segment
#pragma unroll
        for (int j = 0; j < 7; ++j) {
            int i = t * 7 + j;
            if (i < n) { bas[i] = run; cur[i] = run; run += v[j]; }
        }
        if (t == 255) bas[n] = run;            // total
        __syncthreads();
    }
}

// ---------- A3: dual multisplit scatter (exact, chunk-local) ----------
__global__ __launch_bounds__(256) void scatter_kernel(
    const int* __restrict__ in_map, const int* __restrict__ out_map,
    const int* __restrict__ bas_in, const int* __restrict__ bas_out,
    int* __restrict__ cur_in, int* __restrict__ cur_out,
    int* __restrict__ binned_in, int* __restrict__ binned_out,
    int* __restrict__ spill_cnt, int* __restrict__ spill)
{
    __shared__ int hi[NBIN_IN], ho[NBIN_OUT];
    __shared__ int sbi[NBIN_IN], sbo[NBIN_OUT];
    const int t = threadIdx.x;
    const int base = blockIdx.x * BPB;
    for (int c = t; c < NBIN_IN; c += 256) { hi[c] = 0; sbi[c] = bas_in[c]; }
    for (int c = t; c < NBIN_OUT; c += 256) { ho[c] = 0; sbo[c] = bas_out[c]; }
    __syncthreads();
    for (int i = t; i < BPB; i += 256) {
        int p = base + i;
        if (p < NPAIR) {
            atomicAdd(&hi[in_map[p] >> 7], 1);
            atomicAdd(&ho[out_map[p] >> 8], 1);
        }
    }
    __syncthreads();
    for (int c = t; c < NBIN_IN; c += 256) {
        int v = hi[c];
        hi[c] = v ? atomicAdd(&cur_in[c], v) : 0;    // chunk base (absolute)
    }
    for (int c = t; c < NBIN_OUT; c += 256) {
        int v = ho[c];
        ho[c] = v ? atomicAdd(&cur_out[c], v) : 0;
    }
    __syncthreads();
    for (int i = t; i < BPB; i += 256) {
        int p = base + i;
        if (p >= NPAIR) continue;
        int ir = in_map[p];
        int orow = out_map[p];
        int ib = ir >> 7, ob = orow >> 8;
        int slot = atomicAdd(&hi[ib], 1);
        if (slot - sbi[ib] >= LCAP) {                 // ~never (exact counts ≤ LCAP whp)
            int o = atomicAdd(spill_cnt, 1);
            if (o < SPILL_CAP) spill[o] = p;
            continue;
        }
        binned_in[slot] = ((ir & 127) << 5) | (p / MPAIR);
        int os = atomicAdd(&ho[ob], 1);
        if (os - sbo[ob] >= LCAP) {
            int o = atomicAdd(spill_cnt, 1);
            if (o < SPILL_CAP) spill[o] = p;
            continue;
        }
        binned_out[os] = ((orow & 255) << 22) | slot; // slot < 2.7M fits 22 bits
    }
}

// ---------- mv2: in-binned matvec, LDS feats tile, k-sorted SGPR weights ----------
__global__ __launch_bounds__(256) void mv2_kernel(
    const float* __restrict__ feats, const float* __restrict__ weight,
    const int* __restrict__ bas_in, const int* __restrict__ cur_in,
    const int* __restrict__ binned_in, unsigned short* __restrict__ per_off)
{
    __shared__ float ftile[CIN * IN_RPB];    // transposed [ci][r], 16 KB
    __shared__ int sorted[LCAP];             // 8 KB
    __shared__ int kcnt[32], kseg[33], kcur[32];

    const int b = blockIdx.x;
    const int t = threadIdx.x;
    const int rbase = b * IN_RPB;
    const int base = bas_in[b];
    const int n = min(cur_in[b] - base, LCAP);

    // stage feats rows transposed (coalesced global float4 reads)
    for (int i4 = t; i4 < IN_RPB * 8; i4 += 256) {
        int r = i4 >> 3, c4 = i4 & 7;
        int grow = rbase + r;
        float4 v = (grow < NIN)
            ? reinterpret_cast<const float4*>(feats)[(size_t)grow * 8 + c4]
            : make_float4(0.f, 0.f, 0.f, 0.f);
        ftile[(c4 * 4 + 0) * IN_RPB + r] = v.x;
        ftile[(c4 * 4 + 1) * IN_RPB + r] = v.y;
        ftile[(c4 * 4 + 2) * IN_RPB + r] = v.z;
        ftile[(c4 * 4 + 3) * IN_RPB + r] = v.w;
    }
    if (t < 32) kcnt[t] = 0;
    __syncthreads();

    for (int i = t; i < n; i += 256)
        atomicAdd(&kcnt[binned_in[base + i] & 31], 1);
    __syncthreads();
    if (t == 0) {
        int s = 0;
        for (int k = 0; k < 32; ++k) { kseg[k] = s; kcur[k] = s; s += kcnt[k]; }
        kseg[32] = s;
    }
    __syncthreads();
    for (int i = t; i < n; i += 256) {
        int e = binned_in[base + i];
        int pos = atomicAdd(&kcur[e & 31], 1);
        sorted[pos] = (i << 12) | e;          // i<2048 (11b) | rl(7b) | k(5b)
    }
    __syncthreads();

    const int wave = t >> 6, lane = t & 63;
    for (int k = wave; k < KOFF; k += 4) {
        int s0 = kseg[k], s1 = kseg[k + 1];
        const float* wk = weight + (size_t)__builtin_amdgcn_readfirstlane(k) * (CIN * COUT);
        for (int i = s0 + lane; i < s1; i += 64) {
            int e = sorted[i];
            int rl = (e >> 5) & 127;
            int slot = base + (e >> 12);

            float acc[COUT];
#pragma unroll
            for (int j = 0; j < COUT; ++j) acc[j] = 0.f;
#pragma unroll
            for (int ci = 0; ci < CIN; ++ci) {
                float fv = ftile[ci * IN_RPB + rl];
#pragma unroll
                for (int co = 0; co < COUT; ++co)
                    acc[co] = fmaf(fv, wk[ci * COUT + co], acc[co]);
            }
            uint4 u[4];
#pragma unroll
            for (int j = 0; j < 4; ++j) {
                u[j].x = bf16pair(acc[8 * j + 0], acc[8 * j + 1]);
                u[j].y = bf16pair(acc[8 * j + 2], acc[8 * j + 3]);
                u[j].z = bf16pair(acc[8 * j + 4], acc[8 * j + 5]);
                u[j].w = bf16pair(acc[8 * j + 6], acc[8 * j + 7]);
            }
            uint4* dst = reinterpret_cast<uint4*>(per_off + (size_t)slot * COUT);
#pragma unroll
            for (int j = 0; j < 4; ++j) dst[j] = u[j];   // 64B, bin-local window
        }
    }
}

// ---------- gather2: row-sorted, ILP4 random payload reads ----------
__global__ __launch_bounds__(256) void gather2_kernel(
    const unsigned short* __restrict__ per_off,
    const int* __restrict__ bas_out, const int* __restrict__ cur_out,
    const int* __restrict__ binned_out, float* __restrict__ out)
{
    __shared__ int sorted[LCAP];             // 8 KB
    __shared__ int cnt[OUT_RPB], scn[OUT_RPB], cur[OUT_RPB];

    const int b = blockIdx.x;
    const int t = threadIdx.x;
    const int base = bas_out[b];
    const int n = min(cur_out[b] - base, LCAP);

    cnt[t] = 0;
    __syncthreads();
    for (int i = t; i < n; i += 256)
        atomicAdd(&cnt[(binned_out[base + i] >> 22) & 255], 1);
    __syncthreads();
    scn[t] = cnt[t];
    __syncthreads();
    for (int off = 1; off < 256; off <<= 1) {
        int v = (t >= off) ? scn[t - off] : 0;
        __syncthreads();
        scn[t] += v;
        __syncthreads();
    }
    cur[t] = scn[t] - cnt[t];
    __syncthreads();
    for (int i = t; i < n; i += 256) {
        int v = binned_out[base + i];        // L2-hot re-read
        int pos = atomicAdd(&cur[(v >> 22) & 255], 1);
        sorted[pos] = v & 0x3FFFFF;
    }
    __syncthreads();

    const int g = t >> 5, lane = t & 31;
    for (int r = g; r < OUT_RPB; r += 8) {
        int grow = (b << 8) + r;
        if (grow >= NOUT) break;
        int s1 = scn[r], s0 = s1 - cnt[r];
        float a0 = 0.f, a1 = 0.f, a2 = 0.f, a3 = 0.f;
        int i = s0;
        for (; i + 4 <= s1; i += 4) {        // 4 independent loads in flight
            int p0 = sorted[i], p1 = sorted[i + 1], p2 = sorted[i + 2], p3 = sorted[i + 3];
            a0 += bf2f(per_off[(size_t)p0 * COUT + lane]);
            a1 += bf2f(per_off[(size_t)p1 * COUT + lane]);
            a2 += bf2f(per_off[(size_t)p2 * COUT + lane]);
            a3 += bf2f(per_off[(size_t)p3 * COUT + lane]);
        }
        for (; i < s1; ++i)
            a0 += bf2f(per_off[(size_t)sorted[i] * COUT + lane]);
        out[(size_t)grow * COUT + lane] = (a0 + a1) + (a2 + a3);
    }
}

// ---------- spill: recompute rare pairs, f32 atomics ----------
__global__ __launch_bounds__(256) void spill_kernel(
    const float* __restrict__ feats, const float* __restrict__ weight,
    const int* __restrict__ in_map, const int* __restrict__ out_map,
    const int* __restrict__ spill_cnt, const int* __restrict__ spill,
    float* __restrict__ out)
{
    int n = min(*spill_cnt, SPILL_CAP);
    for (int i = blockIdx.x * blockDim.x + threadIdx.x; i < n * 32;
         i += gridDim.x * blockDim.x) {
        int idx = i >> 5, co = i & 31;
        int p = spill[idx];
        int k = p / MPAIR;
        int irow = in_map[p];
        int row = out_map[p];
        const float* f = feats + (size_t)irow * CIN;
        const float* wk = weight + (size_t)k * (CIN * COUT);
        float acc = 0.f;
#pragma unroll
        for (int ci = 0; ci < CIN; ++ci)
            acc = fmaf(f[ci], wk[ci * COUT + co], acc);
        atomicAdd(&out[(size_t)row * COUT + co], acc);
    }
}

// ---------- last-resort fallback (tiny ws): R1 atomic scatter ----------
__global__ __launch_bounds__(256) void spconvt_fallback(
    const float* __restrict__ feats, const float* __restrict__ weight,
    const int* __restrict__ in_map, const int* __restrict__ out_map,
    float* __restrict__ out)
{
    const int k = blockIdx.y;
    const int m = blockIdx.x * blockDim.x + threadIdx.x;
    const bool active = (m < MPAIR);
    const int mm = active ? m : (MPAIR - 1);
    const int pair = k * MPAIR + mm;
    const int in_row = in_map[pair];
    const int out_row = out_map[pair];
    const float4* frow = reinterpret_cast<const float4*>(feats + (size_t)in_row * CIN);
    float4 f4[8];
#pragma unroll
    for (int i = 0; i < 8; ++i) f4[i] = frow[i];
    const float* f = reinterpret_cast<const float*>(f4);
    float acc[COUT];
#pragma unroll
    for (int i = 0; i < COUT; ++i) acc[i] = 0.f;
    const float* wk = weight + (size_t)k * (CIN * COUT);
#pragma unroll
    for (int ci = 0; ci < CIN; ++ci) {
        const float fv = f[ci];
#pragma unroll
        for (int co = 0; co < COUT; ++co)
            acc[co] = fmaf(fv, wk[ci * COUT + co], acc[co]);
    }
    if (active) {
        float* orow = out + (size_t)out_row * COUT;
#pragma unroll
        for (int co = 0; co < COUT; ++co) atomicAdd(orow + co, acc[co]);
    }
}

extern "C" void kernel_launch(void* const* d_in, const int* in_sizes, int n_in,
                              void* d_out, int out_size, void* d_ws, size_t ws_size,
                              hipStream_t stream) {
    const float* feats  = (const float*)d_in[0];
    const float* weight = (const float*)d_in[1];
    const int* in_map   = (const int*)d_in[2];
    const int* out_map  = (const int*)d_in[3];
    float* out          = (float*)d_out;
    char* ws            = (char*)d_ws;

    if (ws_size >= WS_NEED) {
        int* cnt_in     = (int*)(ws + O_CNTI);
        int* cnt_out    = (int*)(ws + O_CNTO);
        int* bas_in     = (int*)(ws + O_BASI);
        int* bas_out    = (int*)(ws + O_BASO);
        int* cur_in     = (int*)(ws + O_CURI);
        int* cur_out    = (int*)(ws + O_CURO);
        int* spill_cnt  = (int*)(ws + O_SPCNT);
        int* spill      = (int*)(ws + O_SPILL);
        int* binned_in  = (int*)(ws + O_BINI);
        int* binned_out = (int*)(ws + O_BINO);
        unsigned short* per_off = (unsigned short*)(ws + O_PEROFF);

        hipMemsetAsync(ws, 0, O_SPILL, stream);   // counts + spill_cnt

        hist_kernel<<<dim3(NBLK_AB), dim3(256), 0, stream>>>(
            in_map, out_map, cnt_in, cnt_out);
        scan_kernel<<<dim3(1), dim3(256), 0, stream>>>(
            cnt_in, cnt_out, bas_in, bas_out, cur_in, cur_out);
        scatter_kernel<<<dim3(NBLK_AB), dim3(256), 0, stream>>>(
            in_map, out_map, bas_in, bas_out, cur_in, cur_out,
            binned_in, binned_out, spill_cnt, spill);
        mv2_kernel<<<dim3(NBIN_IN), dim3(256), 0, stream>>>(
            feats, weight, bas_in, cur_in, binned_in, per_off);
        gather2_kernel<<<dim3(NBIN_OUT), dim3(256), 0, stream>>>(
            per_off, bas_out, cur_out, binned_out, out);
        spill_kernel<<<dim3(64), dim3(256), 0, stream>>>(
            feats, weight, in_map, out_map, spill_cnt, spill, out);
    } else {
        hipMemsetAsync(d_out, 0, (size_t)out_size * sizeof(float), stream);
        spconvt_fallback<<<dim3((MPAIR + 255) / 256, KOFF), dim3(256), 0, stream>>>(
            feats, weight, in_map, out_map, out);
    }
}

// Round 9
// 393.554 us; speedup vs baseline: 2.8802x; 2.8802x over previous
//
#include <hip/hip_runtime.h>

#define KOFF 27
#define MPAIR 100000
#define NPAIR (KOFF * MPAIR)        // 2,700,000
#define NOUT 400000
#define CIN 32
#define COUT 32

#define ROWS_PER_BIN 256
#define NBIN ((NOUT + ROWS_PER_BIN - 1) / ROWS_PER_BIN)   // 1563
#define CAPB 3072                   // per-bin capacity (avg 1728, +32 sigma)
#define BPB 8192                    // pairs per bin_kernel block
#define SPILL_CAP 65536

// ---------- workspace layout (bytes) ----------
// gbin      @ 0          : NBIN*4 -> pad 8192
// spill_cnt @ 8192       : 256
// spill     @ 8448       : SPILL_CAP*8 = 524,288        -> end 532,736
// binned    @ 532,736    : NBIN*CAPB*4 = 19,206,144     -> end 19,738,880
// per_off   @ 19,738,880 : 2.7M*32*2  = 172,800,000     -> end 192,538,880
#define O_SPCNT   ((size_t)8192)
#define O_SPILL   ((size_t)8448)
#define O_BINNED  ((size_t)532736)
#define O_PEROFF  ((size_t)19738880)
#define WS_NEED   ((size_t)192538880)

typedef unsigned int uint4n __attribute__((ext_vector_type(4)));  // native vec for nontemporal

__device__ __forceinline__ unsigned int bf16pair(float a, float b) {
    unsigned int ua = __float_as_uint(a), ub = __float_as_uint(b);
    ua = (ua + 0x7fffu + ((ua >> 16) & 1u)) >> 16;   // RNE
    ub = (ub + 0x7fffu + ((ub >> 16) & 1u)) >> 16;
    return ua | (ub << 16);
}
__device__ __forceinline__ float bf2f(unsigned short v) {
    return __uint_as_float(((unsigned int)v) << 16);
}

// ---------- Phase 1: multisplit pair ids by output-row bin ----------
__global__ __launch_bounds__(256) void bin_kernel(
    const int* __restrict__ out_map,
    int* __restrict__ gbin, int* __restrict__ binned,
    int* __restrict__ spill_cnt, int2* __restrict__ spill)
{
    __shared__ int lhist[NBIN];              // count, then running cursor
    const int t = threadIdx.x;
    const int base = blockIdx.x * BPB;

    for (int c = t; c < NBIN; c += 256) lhist[c] = 0;
    __syncthreads();

    for (int i = t; i < BPB; i += 256) {
        int p = base + i;
        if (p < NPAIR) atomicAdd(&lhist[out_map[p] >> 8], 1);
    }
    __syncthreads();

    for (int c = t; c < NBIN; c += 256) {
        int cnt = lhist[c];
        lhist[c] = (cnt > 0) ? atomicAdd(&gbin[c], cnt) : 0;  // chunk base
    }
    __syncthreads();

    // scatter packed (rowlocal<<22 | pair_id); chunk-local -> good sectors
    for (int i = t; i < BPB; i += 256) {
        int p = base + i;
        if (p >= NPAIR) continue;
        int row = out_map[p];
        int bin = row >> 8;
        int val = ((row & 255) << 22) | p;
        int pos = atomicAdd(&lhist[bin], 1);
        if (pos < CAPB) {
            binned[(size_t)bin * CAPB + pos] = val;
        } else {
            int o = atomicAdd(spill_cnt, 1);
            if (o < SPILL_CAP) spill[o] = make_int2(row, p);
        }
    }
}

// ---------- Phase 2: per-pair matvec, nontemporal contiguous bf16 stores ----------
__global__ __launch_bounds__(256) void mv_kernel(
    const float* __restrict__ feats, const float* __restrict__ weight,
    const int* __restrict__ in_map, unsigned short* __restrict__ per_off)
{
    const int k = blockIdx.y;                 // wave-uniform -> SGPR weights
    const int m = blockIdx.x * 256 + threadIdx.x;
    if (m >= MPAIR) return;
    const int p = k * MPAIR + m;
    const int in_row = in_map[p];

    const float4* frow = reinterpret_cast<const float4*>(feats + (size_t)in_row * CIN);
    float4 f4[8];
#pragma unroll
    for (int i = 0; i < 8; ++i) f4[i] = frow[i];
    const float* f = reinterpret_cast<const float*>(f4);

    float acc[COUT];
#pragma unroll
    for (int i = 0; i < COUT; ++i) acc[i] = 0.f;

    const float* wk = weight + (size_t)k * (CIN * COUT);
#pragma unroll
    for (int ci = 0; ci < CIN; ++ci) {
        const float fv = f[ci];
#pragma unroll
        for (int co = 0; co < COUT; ++co)
            acc[co] = fmaf(fv, wk[ci * COUT + co], acc[co]);
    }

    uint4n u[4];
#pragma unroll
    for (int j = 0; j < 4; ++j) {
        u[j].x = bf16pair(acc[8 * j + 0], acc[8 * j + 1]);
        u[j].y = bf16pair(acc[8 * j + 2], acc[8 * j + 3]);
        u[j].z = bf16pair(acc[8 * j + 4], acc[8 * j + 5]);
        u[j].w = bf16pair(acc[8 * j + 6], acc[8 * j + 7]);
    }
    uint4n* dst = reinterpret_cast<uint4n*>(per_off + (size_t)p * COUT);
#pragma unroll
    for (int j = 0; j < 4; ++j)
        __builtin_nontemporal_store(u[j], dst + j);   // stream past L2
}

// ---------- Phase 3: per-bin counting-sort + ILP4 register-accumulate gather ----------
__global__ __launch_bounds__(256) void gather3_kernel(
    const unsigned short* __restrict__ per_off,
    const int* __restrict__ gbin, const int* __restrict__ binned,
    float* __restrict__ out)
{
    __shared__ int sorted[CAPB];             // 12 KB (no raw[] staging)
    __shared__ int cnt[ROWS_PER_BIN];        // 1 KB
    __shared__ int scn[ROWS_PER_BIN];        // 1 KB
    __shared__ int cur[ROWS_PER_BIN];        // 1 KB

    const int bin = blockIdx.x;
    const int t = threadIdx.x;
    const int n = min(gbin[bin], CAPB);
    const int* mybin = binned + (size_t)bin * CAPB;

    cnt[t] = 0;
    __syncthreads();

    // count (coalesced read 1)
    for (int i = t; i < n; i += 256)
        atomicAdd(&cnt[(mybin[i] >> 22) & 255], 1);
    __syncthreads();

    // Hillis-Steele inclusive scan over 256 counters
    scn[t] = cnt[t];
    __syncthreads();
#pragma unroll
    for (int off = 1; off < 256; off <<= 1) {
        int v = (t >= off) ? scn[t - off] : 0;
        __syncthreads();
        scn[t] += v;
        __syncthreads();
    }
    cur[t] = scn[t] - cnt[t];
    __syncthreads();

    // scatter into row-sorted order (coalesced read 2, cache-hot)
    for (int i = t; i < n; i += 256) {
        int v = mybin[i];
        int pos = atomicAdd(&cur[(v >> 22) & 255], 1);
        sorted[pos] = v & 0x3FFFFF;
    }
    __syncthreads();

    // 32-lane group per row: ILP4 random 64B payload reads
    const int g = t >> 5, lane = t & 31;
    for (int r = g; r < ROWS_PER_BIN; r += 8) {
        int grow = (bin << 8) + r;
        if (grow >= NOUT) break;
        int s1 = scn[r], s0 = s1 - cnt[r];
        float a0 = 0.f, a1 = 0.f, a2 = 0.f, a3 = 0.f;
        int i = s0;
        for (; i + 4 <= s1; i += 4) {        // 4 independent loads in flight
            int p0 = sorted[i], p1 = sorted[i + 1], p2 = sorted[i + 2], p3 = sorted[i + 3];
            a0 += bf2f(per_off[(size_t)p0 * COUT + lane]);
            a1 += bf2f(per_off[(size_t)p1 * COUT + lane]);
            a2 += bf2f(per_off[(size_t)p2 * COUT + lane]);
            a3 += bf2f(per_off[(size_t)p3 * COUT + lane]);
        }
        for (; i < s1; ++i)
            a0 += bf2f(per_off[(size_t)sorted[i] * COUT + lane]);
        out[(size_t)grow * COUT + lane] = (a0 + a1) + (a2 + a3);
    }
}

// ---------- Phase 4: statistically-rare bin overflow, recompute + atomics ----------
__global__ __launch_bounds__(256) void spill_kernel(
    const float* __restrict__ feats, const float* __restrict__ weight,
    const int* __restrict__ in_map,
    const int* __restrict__ spill_cnt, const int2* __restrict__ spill,
    float* __restrict__ out)
{
    int n = min(*spill_cnt, SPILL_CAP);
    for (int i = blockIdx.x * blockDim.x + threadIdx.x; i < n * 32;
         i += gridDim.x * blockDim.x) {
        int idx = i >> 5, co = i & 31;
        int2 s = spill[idx];
        int row = s.x;
        int p   = s.y;
        int k   = p / MPAIR;
        int irow = in_map[p];
        const float* f  = feats + (size_t)irow * CIN;
        const float* wk = weight + (size_t)k * (CIN * COUT);
        float acc = 0.f;
#pragma unroll
        for (int ci = 0; ci < CIN; ++ci)
            acc = fmaf(f[ci], wk[ci * COUT + co], acc);
        atomicAdd(&out[(size_t)row * COUT + co], acc);
    }
}

// ---------- last-resort fallback (tiny ws): R1 atomic scatter ----------
__global__ __launch_bounds__(256) void spconvt_fallback(
    const float* __restrict__ feats, const float* __restrict__ weight,
    const int* __restrict__ in_map, const int* __restrict__ out_map,
    float* __restrict__ out)
{
    const int k = blockIdx.y;
    const int m = blockIdx.x * blockDim.x + threadIdx.x;
    const bool active = (m < MPAIR);
    const int mm = active ? m : (MPAIR - 1);
    const int pair = k * MPAIR + mm;
    const int in_row = in_map[pair];
    const int out_row = out_map[pair];
    const float4* frow = reinterpret_cast<const float4*>(feats + (size_t)in_row * CIN);
    float4 f4[8];
#pragma unroll
    for (int i = 0; i < 8; ++i) f4[i] = frow[i];
    const float* f = reinterpret_cast<const float*>(f4);
    float acc[COUT];
#pragma unroll
    for (int i = 0; i < COUT; ++i) acc[i] = 0.f;
    const float* wk = weight + (size_t)k * (CIN * COUT);
#pragma unroll
    for (int ci = 0; ci < CIN; ++ci) {
        const float fv = f[ci];
#pragma unroll
        for (int co = 0; co < COUT; ++co)
            acc[co] = fmaf(fv, wk[ci * COUT + co], acc[co]);
    }
    if (active) {
        float* orow = out + (size_t)out_row * COUT;
#pragma unroll
        for (int co = 0; co < COUT; ++co) atomicAdd(orow + co, acc[co]);
    }
}

extern "C" void kernel_launch(void* const* d_in, const int* in_sizes, int n_in,
                              void* d_out, int out_size, void* d_ws, size_t ws_size,
                              hipStream_t stream) {
    const float* feats  = (const float*)d_in[0];
    const float* weight = (const float*)d_in[1];
    const int* in_map   = (const int*)d_in[2];
    const int* out_map  = (const int*)d_in[3];
    float* out          = (float*)d_out;
    char* ws            = (char*)d_ws;

    if (ws_size >= WS_NEED) {
        int* gbin               = (int*)(ws);
        int* spill_cnt          = (int*)(ws + O_SPCNT);
        int2* spill             = (int2*)(ws + O_SPILL);
        int* binned             = (int*)(ws + O_BINNED);
        unsigned short* per_off = (unsigned short*)(ws + O_PEROFF);

        (void)hipMemsetAsync(ws, 0, O_SPILL, stream);   // gbin + spill_cnt only

        bin_kernel<<<dim3((NPAIR + BPB - 1) / BPB), dim3(256), 0, stream>>>(
            out_map, gbin, binned, spill_cnt, spill);

        mv_kernel<<<dim3((MPAIR + 255) / 256, KOFF), dim3(256), 0, stream>>>(
            feats, weight, in_map, per_off);

        gather3_kernel<<<dim3(NBIN), dim3(256), 0, stream>>>(
            per_off, gbin, binned, out);

        spill_kernel<<<dim3(64), dim3(256), 0, stream>>>(
            feats, weight, in_map, spill_cnt, spill, out);
    } else {
        (void)hipMemsetAsync(d_out, 0, (size_t)out_size * sizeof(float), stream);
        spconvt_fallback<<<dim3((MPAIR + 255) / 256, KOFF), dim3(256), 0, stream>>>(
            feats, weight, in_map, out_map, out);
    }
}

// Round 10
// 297.062 us; speedup vs baseline: 3.8157x; 1.3248x over previous
//
#include <hip/hip_runtime.h>

#define KOFF 27
#define MPAIR 100000
#define NPAIR (KOFF * MPAIR)        // 2,700,000
#define NIN 200000
#define NOUT 400000
#define CIN 32
#define COUT 32

#define ROWS_PER_BIN 256
#define NBIN ((NOUT + ROWS_PER_BIN - 1) / ROWS_PER_BIN)   // 1563
#define CAPB 3072                   // per-bin capacity (avg 1728, +32 sigma)
#define BPB 8192                    // pairs per bin_kernel block
#define SPILL_CAP 65536

// ---------- workspace layout (bytes) ----------
// gbin      @ 0          : NBIN*4 -> pad 8192
// spill_cnt @ 8192       : 256
// spill     @ 8448       : SPILL_CAP*8 = 524,288        -> end 532,736
// binned    @ 532,736    : NBIN*CAPB*4 = 19,206,144     -> end 19,738,880
// per_off   @ 19,738,880 : 2.7M*32*2  = 172,800,000     -> end 192,538,880
// feats16   @ 192,538,880: 200000*32*2 = 12,800,000     -> end 205,338,880
// (proven available: >= 225,633,280)
#define O_SPCNT   ((size_t)8192)
#define O_SPILL   ((size_t)8448)
#define O_BINNED  ((size_t)532736)
#define O_PEROFF  ((size_t)19738880)
#define O_F16     ((size_t)192538880)
#define WS_NEED   ((size_t)205338880)

typedef unsigned int uint4n __attribute__((ext_vector_type(4)));

__device__ __forceinline__ unsigned int bf16pair(float a, float b) {
    unsigned int ua = __float_as_uint(a), ub = __float_as_uint(b);
    ua = (ua + 0x7fffu + ((ua >> 16) & 1u)) >> 16;   // RNE
    ub = (ub + 0x7fffu + ((ub >> 16) & 1u)) >> 16;
    return ua | (ub << 16);
}
__device__ __forceinline__ float bf2f(unsigned short v) {
    return __uint_as_float(((unsigned int)v) << 16);
}
__device__ __forceinline__ float bf2f_lo(unsigned int w) {
    return __uint_as_float(w << 16);
}
__device__ __forceinline__ float bf2f_hi(unsigned int w) {
    return __uint_as_float(w & 0xFFFF0000u);
}

// ---------- Phase 0: feats f32 -> bf16 (sequential, ~38 MB traffic) ----------
__global__ __launch_bounds__(256) void cvt_kernel(
    const float* __restrict__ feats, unsigned short* __restrict__ f16)
{
    int i = blockIdx.x * 256 + threadIdx.x;          // one thread = 8 elements
    if (i >= NIN * CIN / 8) return;
    const float4* src = reinterpret_cast<const float4*>(feats) + i * 2;
    float4 a = src[0], b = src[1];
    uint4n u;
    u.x = bf16pair(a.x, a.y); u.y = bf16pair(a.z, a.w);
    u.z = bf16pair(b.x, b.y); u.w = bf16pair(b.z, b.w);
    reinterpret_cast<uint4n*>(f16)[i] = u;
}

// ---------- Phase 1: multisplit pair ids by output-row bin ----------
__global__ __launch_bounds__(256) void bin_kernel(
    const int* __restrict__ out_map,
    int* __restrict__ gbin, int* __restrict__ binned,
    int* __restrict__ spill_cnt, int2* __restrict__ spill)
{
    __shared__ int lhist[NBIN];              // count, then running cursor
    const int t = threadIdx.x;
    const int base = blockIdx.x * BPB;

    for (int c = t; c < NBIN; c += 256) lhist[c] = 0;
    __syncthreads();

    for (int i = t; i < BPB; i += 256) {
        int p = base + i;
        if (p < NPAIR) atomicAdd(&lhist[out_map[p] >> 8], 1);
    }
    __syncthreads();

    for (int c = t; c < NBIN; c += 256) {
        int cnt = lhist[c];
        lhist[c] = (cnt > 0) ? atomicAdd(&gbin[c], cnt) : 0;  // chunk base
    }
    __syncthreads();

    for (int i = t; i < BPB; i += 256) {
        int p = base + i;
        if (p >= NPAIR) continue;
        int row = out_map[p];
        int bin = row >> 8;
        int val = ((row & 255) << 22) | p;
        int pos = atomicAdd(&lhist[bin], 1);
        if (pos < CAPB) {
            binned[(size_t)bin * CAPB + pos] = val;
        } else {
            int o = atomicAdd(spill_cnt, 1);
            if (o < SPILL_CAP) spill[o] = make_int2(row, p);
        }
    }
}

// ---------- Phase 2: per-pair matvec, bf16 feats gather, plain stores ----------
__global__ __launch_bounds__(256) void mv_kernel(
    const unsigned short* __restrict__ f16, const float* __restrict__ weight,
    const int* __restrict__ in_map, unsigned short* __restrict__ per_off)
{
    const int k = blockIdx.y;                 // wave-uniform -> SGPR weights
    const int m = blockIdx.x * 256 + threadIdx.x;
    if (m >= MPAIR) return;
    const int p = k * MPAIR + m;
    const int in_row = in_map[p];

    // 64B random gather (was 128B f32)
    const uint4n* frow = reinterpret_cast<const uint4n*>(f16 + (size_t)in_row * CIN);
    uint4n q[2];
    q[0] = frow[0]; q[1] = frow[1];

    float f[CIN];
#pragma unroll
    for (int j = 0; j < 2; ++j) {
        f[j*16 + 0]  = bf2f_lo(q[j].x); f[j*16 + 1]  = bf2f_hi(q[j].x);
        f[j*16 + 2]  = bf2f_lo(q[j].y); f[j*16 + 3]  = bf2f_hi(q[j].y);
        f[j*16 + 4]  = bf2f_lo(q[j].z); f[j*16 + 5]  = bf2f_hi(q[j].z);
        f[j*16 + 6]  = bf2f_lo(q[j].w); f[j*16 + 7]  = bf2f_hi(q[j].w);
    }
    // note: uint4n has 4 comps of 4B = 8 bf16; two loads = 16... need 32 bf16 = 64B
    // q[0]=bytes 0..15 (8 vals), q[1]=16..31 (8 vals) -> only 16 values. Load 2 more:
    uint4n q2[2];
    q2[0] = frow[2]; q2[1] = frow[3];
#pragma unroll
    for (int j = 0; j < 2; ++j) {
        f[16 + j*8 + 0] = bf2f_lo(q2[j].x); f[16 + j*8 + 1] = bf2f_hi(q2[j].x);
        f[16 + j*8 + 2] = bf2f_lo(q2[j].y); f[16 + j*8 + 3] = bf2f_hi(q2[j].y);
        f[16 + j*8 + 4] = bf2f_lo(q2[j].z); f[16 + j*8 + 5] = bf2f_hi(q2[j].z);
        f[16 + j*8 + 6] = bf2f_lo(q2[j].w); f[16 + j*8 + 7] = bf2f_hi(q2[j].w);
    }
    // fix indexing of first block: q[0]/q[1] hold f[0..15]
    // (f[0..7] from q[0], f[8..15] from q[1]) — rewrite cleanly:
#pragma unroll
    for (int j = 0; j < 2; ++j) {
        f[j*8 + 0] = bf2f_lo(q[j].x); f[j*8 + 1] = bf2f_hi(q[j].x);
        f[j*8 + 2] = bf2f_lo(q[j].y); f[j*8 + 3] = bf2f_hi(q[j].y);
        f[j*8 + 4] = bf2f_lo(q[j].z); f[j*8 + 5] = bf2f_hi(q[j].z);
        f[j*8 + 6] = bf2f_lo(q[j].w); f[j*8 + 7] = bf2f_hi(q[j].w);
    }

    float acc[COUT];
#pragma unroll
    for (int i = 0; i < COUT; ++i) acc[i] = 0.f;

    const float* wk = weight + (size_t)k * (CIN * COUT);
#pragma unroll
    for (int ci = 0; ci < CIN; ++ci) {
        const float fv = f[ci];
#pragma unroll
        for (int co = 0; co < COUT; ++co)
            acc[co] = fmaf(fv, wk[ci * COUT + co], acc[co]);
    }

    uint4n u[4];
#pragma unroll
    for (int j = 0; j < 4; ++j) {
        u[j].x = bf16pair(acc[8 * j + 0], acc[8 * j + 1]);
        u[j].y = bf16pair(acc[8 * j + 2], acc[8 * j + 3]);
        u[j].z = bf16pair(acc[8 * j + 4], acc[8 * j + 5]);
        u[j].w = bf16pair(acc[8 * j + 6], acc[8 * j + 7]);
    }
    uint4n* dst = reinterpret_cast<uint4n*>(per_off + (size_t)p * COUT);
#pragma unroll
    for (int j = 0; j < 4; ++j) dst[j] = u[j];       // plain: L2 write-combines
}

// ---------- Phase 3: per-bin counting-sort + ILP4 register-accumulate gather ----------
__global__ __launch_bounds__(256) void gather3_kernel(
    const unsigned short* __restrict__ per_off,
    const int* __restrict__ gbin, const int* __restrict__ binned,
    float* __restrict__ out)
{
    __shared__ int sorted[CAPB];             // 12 KB
    __shared__ int cnt[ROWS_PER_BIN];
    __shared__ int scn[ROWS_PER_BIN];
    __shared__ int cur[ROWS_PER_BIN];

    const int bin = blockIdx.x;
    const int t = threadIdx.x;
    const int n = min(gbin[bin], CAPB);
    const int* mybin = binned + (size_t)bin * CAPB;

    cnt[t] = 0;
    __syncthreads();

    for (int i = t; i < n; i += 256)
        atomicAdd(&cnt[(mybin[i] >> 22) & 255], 1);
    __syncthreads();

    scn[t] = cnt[t];
    __syncthreads();
#pragma unroll
    for (int off = 1; off < 256; off <<= 1) {
        int v = (t >= off) ? scn[t - off] : 0;
        __syncthreads();
        scn[t] += v;
        __syncthreads();
    }
    cur[t] = scn[t] - cnt[t];
    __syncthreads();

    for (int i = t; i < n; i += 256) {
        int v = mybin[i];
        int pos = atomicAdd(&cur[(v >> 22) & 255], 1);
        sorted[pos] = v & 0x3FFFFF;
    }
    __syncthreads();

    const int g = t >> 5, lane = t & 31;
    for (int r = g; r < ROWS_PER_BIN; r += 8) {
        int grow = (bin << 8) + r;
        if (grow >= NOUT) break;
        int s1 = scn[r], s0 = s1 - cnt[r];
        float a0 = 0.f, a1 = 0.f, a2 = 0.f, a3 = 0.f;
        int i = s0;
        for (; i + 4 <= s1; i += 4) {
            int p0 = sorted[i], p1 = sorted[i + 1], p2 = sorted[i + 2], p3 = sorted[i + 3];
            a0 += bf2f(per_off[(size_t)p0 * COUT + lane]);
            a1 += bf2f(per_off[(size_t)p1 * COUT + lane]);
            a2 += bf2f(per_off[(size_t)p2 * COUT + lane]);
            a3 += bf2f(per_off[(size_t)p3 * COUT + lane]);
        }
        for (; i < s1; ++i)
            a0 += bf2f(per_off[(size_t)sorted[i] * COUT + lane]);
        out[(size_t)grow * COUT + lane] = (a0 + a1) + (a2 + a3);
    }
}

// ---------- Phase 4: statistically-rare bin overflow, recompute + atomics ----------
__global__ __launch_bounds__(256) void spill_kernel(
    const float* __restrict__ feats, const float* __restrict__ weight,
    const int* __restrict__ in_map,
    const int* __restrict__ spill_cnt, const int2* __restrict__ spill,
    float* __restrict__ out)
{
    int n = min(*spill_cnt, SPILL_CAP);
    for (int i = blockIdx.x * blockDim.x + threadIdx.x; i < n * 32;
         i += gridDim.x * blockDim.x) {
        int idx = i >> 5, co = i & 31;
        int2 s = spill[idx];
        int row = s.x;
        int p   = s.y;
        int k   = p / MPAIR;
        int irow = in_map[p];
        const float* f  = feats + (size_t)irow * CIN;
        const float* wk = weight + (size_t)k * (CIN * COUT);
        float acc = 0.f;
#pragma unroll
        for (int ci = 0; ci < CIN; ++ci)
            acc = fmaf(f[ci], wk[ci * COUT + co], acc);
        atomicAdd(&out[(size_t)row * COUT + co], acc);
    }
}

// ---------- last-resort fallback (tiny ws): R1 atomic scatter ----------
__global__ __launch_bounds__(256) void spconvt_fallback(
    const float* __restrict__ feats, const float* __restrict__ weight,
    const int* __restrict__ in_map, const int* __restrict__ out_map,
    float* __restrict__ out)
{
    const int k = blockIdx.y;
    const int m = blockIdx.x * blockDim.x + threadIdx.x;
    const bool active = (m < MPAIR);
    const int mm = active ? m : (MPAIR - 1);
    const int pair = k * MPAIR + mm;
    const int in_row = in_map[pair];
    const int out_row = out_map[pair];
    const float4* frow = reinterpret_cast<const float4*>(feats + (size_t)in_row * CIN);
    float4 f4[8];
#pragma unroll
    for (int i = 0; i < 8; ++i) f4[i] = frow[i];
    const float* f = reinterpret_cast<const float*>(f4);
    float acc[COUT];
#pragma unroll
    for (int i = 0; i < COUT; ++i) acc[i] = 0.f;
    const float* wk = weight + (size_t)k * (CIN * COUT);
#pragma unroll
    for (int ci = 0; ci < CIN; ++ci) {
        const float fv = f[ci];
#pragma unroll
        for (int co = 0; co < COUT; ++co)
            acc[co] = fmaf(fv, wk[ci * COUT + co], acc[co]);
    }
    if (active) {
        float* orow = out + (size_t)out_row * COUT;
#pragma unroll
        for (int co = 0; co < COUT; ++co) atomicAdd(orow + co, acc[co]);
    }
}

extern "C" void kernel_launch(void* const* d_in, const int* in_sizes, int n_in,
                              void* d_out, int out_size, void* d_ws, size_t ws_size,
                              hipStream_t stream) {
    const float* feats  = (const float*)d_in[0];
    const float* weight = (const float*)d_in[1];
    const int* in_map   = (const int*)d_in[2];
    const int* out_map  = (const int*)d_in[3];
    float* out          = (float*)d_out;
    char* ws            = (char*)d_ws;

    if (ws_size >= WS_NEED) {
        int* gbin               = (int*)(ws);
        int* spill_cnt          = (int*)(ws + O_SPCNT);
        int2* spill             = (int2*)(ws + O_SPILL);
        int* binned             = (int*)(ws + O_BINNED);
        unsigned short* per_off = (unsigned short*)(ws + O_PEROFF);
        unsigned short* f16     = (unsigned short*)(ws + O_F16);

        (void)hipMemsetAsync(ws, 0, O_SPILL, stream);   // gbin + spill_cnt only

        cvt_kernel<<<dim3((NIN * CIN / 8 + 255) / 256), dim3(256), 0, stream>>>(
            feats, f16);

        bin_kernel<<<dim3((NPAIR + BPB - 1) / BPB), dim3(256), 0, stream>>>(
            out_map, gbin, binned, spill_cnt, spill);

        mv_kernel<<<dim3((MPAIR + 255) / 256, KOFF), dim3(256), 0, stream>>>(
            f16, weight, in_map, per_off);

        gather3_kernel<<<dim3(NBIN), dim3(256), 0, stream>>>(
            per_off, gbin, binned, out);

        spill_kernel<<<dim3(64), dim3(256), 0, stream>>>(
            feats, weight, in_map, spill_cnt, spill, out);
    } else {
        (void)hipMemsetAsync(d_out, 0, (size_t)out_size * sizeof(float), stream);
        spconvt_fallback<<<dim3((MPAIR + 255) / 256, KOFF), dim3(256), 0, stream>>>(
            feats, weight, in_map, out_map, out);
    }
}